// Round 6
// baseline (521.817 us; speedup 1.0000x reference)
//
#include <hip/hip_runtime.h>

#define DD 128
typedef unsigned int u32;
typedef __attribute__((ext_vector_type(8))) short bf16x8;
typedef __attribute__((ext_vector_type(4))) float f32x4;

__device__ __forceinline__ float lrelu(float v, float s) { return v >= 0.f ? v : s * v; }
__device__ __forceinline__ ushort f2bf(float f) {
  union { float f; u32 u; } v; v.f = f;
  u32 u = v.u;
  return (ushort)((u + 0x7FFFu + ((u >> 16) & 1u)) >> 16);  // RNE
}

// ---------------- prep: W^T -> bf16 MFMA A-fragment layout ----------------
__global__ __launch_bounds__(256) void k_prep_w(const float* __restrict__ W,
                                                short* __restrict__ WA)
{
  int t = blockIdx.x * 256 + threadIdx.x;  // 6144
  int lane = t & 63, ks = (t >> 6) & 3, cf = (t >> 8) & 7, r = t >> 11;
  int c = cf * 16 + (lane & 15);
  int kb = ks * 32 + (lane >> 4) * 8;
  const float* Wr = W + (size_t)r * DD * DD;
  ushort o[8];
#pragma unroll
  for (int j = 0; j < 8; j++) o[j] = f2bf(Wr[(size_t)(kb + j) * DD + c]);
  uint4 st;
  st.x = (u32)o[0] | ((u32)o[1] << 16);
  st.y = (u32)o[2] | ((u32)o[3] << 16);
  st.z = (u32)o[4] | ((u32)o[5] << 16);
  st.w = (u32)o[6] | ((u32)o[7] << 16);
  *(uint4*)(WA + (size_t)t * 8) = st;
}

// ---------------- prep: bi_w/si_w -> bf16 A-frags ----------------
__global__ __launch_bounds__(256) void k_prep_cw(const float* __restrict__ bw,
                                                 const float* __restrict__ sw,
                                                 short* __restrict__ WB)
{
  int t = blockIdx.x * 256 + threadIdx.x;  // 4096
  int lane = t & 63, ks = (t >> 6) & 3, cf = (t >> 8) & 7, m = t >> 11;
  const float* src = m ? sw : bw;
  int c = cf * 16 + (lane & 15);
  int k = ks * 32 + (lane >> 4) * 8;
  const float* pr = src + (size_t)c * DD + k;
  uint4 st;
  st.x = (u32)f2bf(pr[0]) | ((u32)f2bf(pr[1]) << 16);
  st.y = (u32)f2bf(pr[2]) | ((u32)f2bf(pr[3]) << 16);
  st.z = (u32)f2bf(pr[4]) | ((u32)f2bf(pr[5]) << 16);
  st.w = (u32)f2bf(pr[6]) | ((u32)f2bf(pr[7]) << 16);
  *(uint4*)(WB + (size_t)t * 8) = st;
}

// ---------------- prep: wl = W @ attn_l, wr = W @ attn_r ----------------
__global__ void k_prep_av(const float* __restrict__ W, const float* __restrict__ al,
                          const float* __restrict__ ar, float* __restrict__ wl,
                          float* __restrict__ wr)
{
  int t = blockIdx.x * 192 + threadIdx.x;  // 384
  if (t >= 384) return;
  int r = t >> 7, k = t & 127;
  const float* Wrow = W + (size_t)r * DD * DD + (size_t)k * DD;
  const float* alr = al + r * DD;
  const float* arr = ar + r * DD;
  float pl = 0.f, pr = 0.f;
  for (int c = 0; c < DD; c++) { float w = Wrow[c]; pl = fmaf(w, alr[c], pl); pr = fmaf(w, arr[c], pr); }
  wl[t] = pl; wr[t] = pr;
}

// ---------------- prep: x -> bf16 rows (u32/lane) + el/er = x.wl / x.wr ----------------
// one wave per node; lane owns channels 2l, 2l+1.
__global__ __launch_bounds__(256) void k_prep_xrow(
    const float* __restrict__ x, const float* __restrict__ wl, const float* __restrict__ wr,
    u32* __restrict__ xrow, float* __restrict__ el, float* __restrict__ er, int N)
{
  const int wid = (int)(((long long)blockIdx.x * 256 + threadIdx.x) >> 6);
  const int lane = threadIdx.x & 63;
  if (wid >= N) return;
  float2 xv = *(const float2*)(x + (size_t)wid * DD + lane * 2);
  xrow[(size_t)wid * 64 + lane] = (u32)f2bf(xv.x) | ((u32)f2bf(xv.y) << 16);
  float d[6];
#pragma unroll
  for (int r = 0; r < 3; r++) {
    float2 wlv = *(const float2*)(wl + r * DD + lane * 2);
    float2 wrv = *(const float2*)(wr + r * DD + lane * 2);
    d[r]     = xv.x * wlv.x + xv.y * wlv.y;
    d[r + 3] = xv.x * wrv.x + xv.y * wrv.y;
  }
#pragma unroll
  for (int o = 32; o; o >>= 1) {
#pragma unroll
    for (int k = 0; k < 6; k++) d[k] += __shfl_xor(d[k], o);
  }
  if (lane == 0) {
#pragma unroll
    for (int r = 0; r < 3; r++) {
      el[(size_t)r * N + wid] = d[r];
      er[(size_t)r * N + wid] = d[r + 3];
    }
  }
}

// ---------------- CSR build: histogram of dst (grid.y = r) ----------------
__global__ void k_hist3(const int* __restrict__ dst, int* __restrict__ cnt, int N, int E) {
  int i = blockIdx.x * 256 + threadIdx.x;
  int r = blockIdx.y;
  if (i < E) atomicAdd(cnt + (size_t)r * N + dst[(size_t)r * E + i], 1);
}

// ---------------- hierarchical scan: base[0..M] ----------------
__global__ __launch_bounds__(256) void k_scan_bsum(const int* __restrict__ cnt,
                                                   int* __restrict__ bsum, int M)
{
  __shared__ int red[256];
  const int t = threadIdx.x;
  const int g0 = blockIdx.x * 2048 + t * 8;
  int s = 0;
#pragma unroll
  for (int j = 0; j < 8; j++) { int i = g0 + j; if (i < M) s += cnt[i]; }
  red[t] = s;
  __syncthreads();
  for (int o = 128; o; o >>= 1) {
    if (t < o) red[t] += red[t + o];
    __syncthreads();
  }
  if (t == 0) bsum[blockIdx.x] = red[0];
}

__global__ __launch_bounds__(256) void k_scan_btop(const int* __restrict__ bsum,
                                                   int* __restrict__ bpre, int NB)
{
  __shared__ int sums[256];
  const int t = threadIdx.x;
  int v = (t < NB) ? bsum[t] : 0;
  sums[t] = v;
  __syncthreads();
  for (int o = 1; o < 256; o <<= 1) {
    int u = (t >= o) ? sums[t - o] : 0;
    __syncthreads();
    sums[t] += u;
    __syncthreads();
  }
  if (t < NB) bpre[t] = sums[t] - v;
}

__global__ __launch_bounds__(256) void k_scan_base(const int* __restrict__ cnt,
    const int* __restrict__ bpre, int* __restrict__ base, int M)
{
  __shared__ int sums[256];
  const int t = threadIdx.x;
  const int g0 = blockIdx.x * 2048 + t * 8;
  int c[8];
  int ts = 0;
#pragma unroll
  for (int j = 0; j < 8; j++) { int i = g0 + j; c[j] = (i < M) ? cnt[i] : 0; ts += c[j]; }
  sums[t] = ts;
  __syncthreads();
  for (int o = 1; o < 256; o <<= 1) {
    int u = (t >= o) ? sums[t - o] : 0;
    __syncthreads();
    sums[t] += u;
    __syncthreads();
  }
  int run = bpre[blockIdx.x] + sums[t] - ts;
#pragma unroll
  for (int j = 0; j < 8; j++) {
    int i = g0 + j;
    if (i <= M) base[i] = run;
    run += c[j];
  }
}

// ---------------- scatter: CSR edge-index permutation only ----------------
__global__ void k_scatter3(const int* __restrict__ dst, const int* __restrict__ base,
                           int* __restrict__ cnt, int* __restrict__ eperm, int N, int E)
{
  int i = blockIdx.x * 256 + threadIdx.x;
  if (i >= E) return;
  int r = blockIdx.y;
  size_t node = (size_t)r * N + dst[(size_t)r * E + i];
  int pos = base[node] + (atomicSub(cnt + node, 1) - 1);
  eperm[pos] = i;
}

// ---------------- per-node softmax + x-aggregation, all 3 relations ----------------
// one wave per node; lane owns channels 2l,2l+1; 8 loads in flight per chunk.
// out: aggx_r[node] = (1/ssum) * sum_e alpha_e * x_bf16[src_e]   (bf16 rows)
__global__ __launch_bounds__(256) void k_node_agg3(
    const int* __restrict__ base, const int* __restrict__ eperm,
    const int* __restrict__ esrc, const float* __restrict__ ew,
    const float* __restrict__ el, const float* __restrict__ er,
    const u32* __restrict__ xrow, u32* __restrict__ aggx, int N, int Np, int E)
{
  const int wid = (int)(((long long)blockIdx.x * 256 + threadIdx.x) >> 6);
  const int lane = threadIdx.x & 63;
  if (wid >= N) return;
  const char* xb = (const char*)xrow;
  const u32 lb = (u32)lane << 2;

  for (int r = 0; r < 3; r++) {
    const int nid = r * N + wid;
    const int b0 = base[nid];
    const int deg = base[nid + 1] - b0;
    const int* esrc_r = esrc + (size_t)r * E;
    const float* ew_r = ew + (size_t)r * E;
    const float* el_r = el + (size_t)r * N;
    float a0 = 0.f, a1 = 0.f, ssum = 0.f;

    if (deg > 0) {
      const float ern = er[nid];
      if (deg <= 64) {
        float e = -1e30f, cw = 0.f; int sv = 0;
        if (lane < deg) {
          int eidx = eperm[b0 + lane];
          sv = esrc_r[eidx];
          e = lrelu(el_r[sv] + ern, 0.2f);
          cw = ew_r[eidx];
        }
        float m = e;
#pragma unroll
        for (int o = 32; o; o >>= 1) m = fmaxf(m, __shfl_xor(m, o));
        float a = 0.f;
        if (lane < deg) { a = __expf(e - m); cw *= a; }
        ssum = a;
#pragma unroll
        for (int o = 32; o; o >>= 1) ssum += __shfl_xor(ssum, o);
        // gather: 8-edge chunks, all loads independent (cw==0 past deg -> dummy row 0)
        for (int c8 = 0; c8 < deg; c8 += 8) {
          float cc[8]; u32 oo[8];
#pragma unroll
          for (int q = 0; q < 8; q++) {
            int j = c8 + q;
            cc[q] = __shfl(cw, j);
            oo[q] = ((u32)__shfl(sv, j) << 8) | lb;
          }
          u32 uu[8];
#pragma unroll
          for (int q = 0; q < 8; q++) uu[q] = *(const u32*)(xb + oo[q]);
#pragma unroll
          for (int q = 0; q < 8; q++) {
            a0 = fmaf(cc[q], __uint_as_float(uu[q] << 16), a0);
            a1 = fmaf(cc[q], __uint_as_float(uu[q] & 0xFFFF0000u), a1);
          }
        }
      } else {
        float m = -1e30f;
        for (int j2 = lane; j2 < deg; j2 += 64) {
          int eidx = eperm[b0 + j2];
          m = fmaxf(m, lrelu(el_r[esrc_r[eidx]] + ern, 0.2f));
        }
#pragma unroll
        for (int o = 32; o; o >>= 1) m = fmaxf(m, __shfl_xor(m, o));
        for (int c0 = 0; c0 < deg; c0 += 64) {
          int kk = min(64, deg - c0);
          float a = 0.f, cw = 0.f; int sv = 0;
          if (lane < kk) {
            int eidx = eperm[b0 + c0 + lane];
            sv = esrc_r[eidx];
            float e = lrelu(el_r[sv] + ern, 0.2f);
            a = __expf(e - m);
            cw = a * ew_r[eidx];
          }
          ssum += a;
          for (int c8 = 0; c8 < kk; c8 += 8) {
            float cc[8]; u32 oo[8];
#pragma unroll
            for (int q = 0; q < 8; q++) {
              int j = c8 + q;
              cc[q] = __shfl(cw, j);
              oo[q] = ((u32)__shfl(sv, j) << 8) | lb;
            }
            u32 uu[8];
#pragma unroll
            for (int q = 0; q < 8; q++) uu[q] = *(const u32*)(xb + oo[q]);
#pragma unroll
            for (int q = 0; q < 8; q++) {
              a0 = fmaf(cc[q], __uint_as_float(uu[q] << 16), a0);
              a1 = fmaf(cc[q], __uint_as_float(uu[q] & 0xFFFF0000u), a1);
            }
          }
        }
#pragma unroll
        for (int o = 32; o; o >>= 1) ssum += __shfl_xor(ssum, o);
      }
    }
    const float inv = (deg > 0) ? 1.f / ssum : 0.f;
    aggx[((size_t)r * Np + wid) * 64 + lane] =
        (u32)f2bf(a0 * inv) | ((u32)f2bf(a1 * inv) << 16);
  }
}

// ---------------- MFMA: feats_r = aggx_r @ W_r + gb_r; s,q,dfm -> bf16 rows ----------------
// 4 waves x 16 nodes per block.
__global__ __launch_bounds__(256) void k_mfma_feats(
    const u32* __restrict__ aggx, const short* __restrict__ WA,
    const float* __restrict__ gb, short* __restrict__ sbuf, short* __restrict__ dbuf,
    int N, int Np)
{
  const int lane = threadIdx.x & 63;
  const int w = threadIdx.x >> 6;
  const int n0 = blockIdx.x * 64 + w * 16;
  const int node = n0 + (lane & 15);
  const int fh8 = (lane >> 4) * 8;
  const int fh4 = (lane >> 4) * 4;
  const short* ax = (const short*)aggx;

  f32x4 sa[8], qa[8];
#pragma unroll
  for (int cf = 0; cf < 8; cf++) { sa[cf] = (f32x4){0,0,0,0}; qa[cf] = (f32x4){0,0,0,0}; }

  for (int r = 0; r < 3; r++) {
    bf16x8 bf[4];
#pragma unroll
    for (int ks = 0; ks < 4; ks++)
      bf[ks] = *(const bf16x8*)(ax + ((size_t)r * Np + node) * DD + ks * 32 + fh8);
    f32x4 acc[8];
#pragma unroll
    for (int cf = 0; cf < 8; cf++) acc[cf] = (f32x4){0,0,0,0};
#pragma unroll
    for (int ks = 0; ks < 4; ks++) {
#pragma unroll
      for (int cf = 0; cf < 8; cf++) {
        bf16x8 af = *(const bf16x8*)(WA + ((((size_t)r * 8 + cf) * 4 + ks) * 64 + lane) * 8);
        acc[cf] = __builtin_amdgcn_mfma_f32_16x16x32_bf16(af, bf[ks], acc[cf], 0, 0, 0);
      }
    }
#pragma unroll
    for (int cf = 0; cf < 8; cf++) {
      float4 g4 = *(const float4*)(gb + r * DD + cf * 16 + fh4);
      const float* gp = (const float*)&g4;
#pragma unroll
      for (int j = 0; j < 4; j++) {
        float f = acc[cf][j] + gp[j];
        sa[cf][j] += f;
        qa[cf][j] += f * f;
      }
    }
  }
  if (node < N) {
#pragma unroll
    for (int cf = 0; cf < 8; cf++) {
      size_t off = (size_t)node * DD + cf * 16 + fh4;
      float d0 = 0.5f * (sa[cf][0] * sa[cf][0] - qa[cf][0]);
      float d1 = 0.5f * (sa[cf][1] * sa[cf][1] - qa[cf][1]);
      float d2 = 0.5f * (sa[cf][2] * sa[cf][2] - qa[cf][2]);
      float d3 = 0.5f * (sa[cf][3] * sa[cf][3] - qa[cf][3]);
      uint2 us, ud;
      us.x = (u32)f2bf(sa[cf][0]) | ((u32)f2bf(sa[cf][1]) << 16);
      us.y = (u32)f2bf(sa[cf][2]) | ((u32)f2bf(sa[cf][3]) << 16);
      ud.x = (u32)f2bf(d0) | ((u32)f2bf(d1) << 16);
      ud.y = (u32)f2bf(d2) | ((u32)f2bf(d3) << 16);
      *(uint2*)(sbuf + off) = us;
      *(uint2*)(dbuf + off) = ud;
    }
  }
}

// ---------------- combine via MFMA + LayerNorm ----------------
__global__ __launch_bounds__(256) void k_combine_mfma(
    const short* __restrict__ sb, const short* __restrict__ db,
    const float* __restrict__ x, const short* __restrict__ WB,
    const float* __restrict__ bi_b, const float* __restrict__ si_b,
    const float* __restrict__ res_w, const float* __restrict__ ln_g,
    const float* __restrict__ ln_b, float* __restrict__ out, int N)
{
  const int lane = threadIdx.x & 63;
  const int w = threadIdx.x >> 6;
  const int n0 = blockIdx.x * 128 + w * 32;
  const float sigw = 1.f / (1.f + __expf(-res_w[0]));
  const int fh4 = (lane >> 4) << 2;

  for (int nf = 0; nf < 2; nf++) {
    const int node = n0 + nf * 16 + (lane & 15);
    const size_t rowo = (size_t)node * DD + ((lane >> 4) << 3);
    bf16x8 sf[4], df[4];
#pragma unroll
    for (int ks = 0; ks < 4; ks++) {
      sf[ks] = *(const bf16x8*)(sb + rowo + ks * 32);
      df[ks] = *(const bf16x8*)(db + rowo + ks * 32);
    }
    f32x4 accB[8], accS[8];
#pragma unroll
    for (int cf = 0; cf < 8; cf++) {
      accB[cf] = (f32x4){0.f, 0.f, 0.f, 0.f};
      accS[cf] = (f32x4){0.f, 0.f, 0.f, 0.f};
    }
#pragma unroll
    for (int ks = 0; ks < 4; ks++) {
#pragma unroll
      for (int cf = 0; cf < 8; cf++) {
        bf16x8 ab = *(const bf16x8*)(WB + ((((size_t)0 * 8 + cf) * 4 + ks) * 64 + lane) * 8);
        bf16x8 as = *(const bf16x8*)(WB + ((((size_t)1 * 8 + cf) * 4 + ks) * 64 + lane) * 8);
        accB[cf] = __builtin_amdgcn_mfma_f32_16x16x32_bf16(ab, df[ks], accB[cf], 0, 0, 0);
        accS[cf] = __builtin_amdgcn_mfma_f32_16x16x32_bf16(as, sf[ks], accS[cf], 0, 0, 0);
      }
    }

    float vals[8][4];
    float sv = 0.f, sq = 0.f;
#pragma unroll
    for (int cf = 0; cf < 8; cf++) {
      int c0 = cf * 16 + fh4;
      float4 bb4 = *(const float4*)(bi_b + c0);
      float4 sb4 = *(const float4*)(si_b + c0);
      float4 xv = make_float4(0.f, 0.f, 0.f, 0.f);
      if (node < N) xv = *(const float4*)(x + (size_t)node * DD + c0);
      const float* bbp = (const float*)&bb4;
      const float* sbp = (const float*)&sb4;
      const float* xvp = (const float*)&xv;
#pragma unroll
      for (int j = 0; j < 4; j++) {
        float val = lrelu(accB[cf][j] + bbp[j], 0.01f)
                  + lrelu(accS[cf][j] + sbp[j], 0.01f)
                  + xvp[j] * sigw;
        vals[cf][j] = val;
        sv += val; sq += val * val;
      }
    }
    sv += __shfl_xor(sv, 16); sq += __shfl_xor(sq, 16);
    sv += __shfl_xor(sv, 32); sq += __shfl_xor(sq, 32);
    const float mu = sv * (1.f / DD);
    const float var = sq * (1.f / DD) - mu * mu;
    const float rs = rsqrtf(var + 1e-5f);
    if (node < N) {
#pragma unroll
      for (int cf = 0; cf < 8; cf++) {
        int c0 = cf * 16 + fh4;
        float4 g4 = *(const float4*)(ln_g + c0);
        float4 b4 = *(const float4*)(ln_b + c0);
        float4 o;
        o.x = (vals[cf][0] - mu) * rs * g4.x + b4.x;
        o.y = (vals[cf][1] - mu) * rs * g4.y + b4.y;
        o.z = (vals[cf][2] - mu) * rs * g4.z + b4.z;
        o.w = (vals[cf][3] - mu) * rs * g4.w + b4.w;
        *(float4*)(out + (size_t)node * DD + c0) = o;
      }
    }
  }
}

extern "C" void kernel_launch(void* const* d_in, const int* in_sizes, int n_in,
                              void* d_out, int out_size, void* d_ws, size_t ws_size,
                              hipStream_t stream)
{
  const float* x    = (const float*)d_in[0];
  const int*   esrc = (const int*)d_in[1];
  const int*   edst = (const int*)d_in[2];
  const float* ew   = (const float*)d_in[3];
  const float* W    = (const float*)d_in[4];
  const float* al   = (const float*)d_in[5];
  const float* ar   = (const float*)d_in[6];
  const float* gb   = (const float*)d_in[7];
  const float* bi_w = (const float*)d_in[8];
  const float* bi_b = (const float*)d_in[9];
  const float* si_w = (const float*)d_in[10];
  const float* si_b = (const float*)d_in[11];
  const float* res_w= (const float*)d_in[12];
  const float* ln_g = (const float*)d_in[13];
  const float* ln_b = (const float*)d_in[14];

  const int N = in_sizes[0] / DD;
  const int R = 3;
  const int E = in_sizes[1] / R;
  const int Np = ((N + 127) / 128) * 128;
  const int M = R * N;
  const int NB = (M + 2047) / 2048;

  auto al256 = [](size_t v) { return (v + 255) & ~(size_t)255; };
  char* p = (char*)d_ws;
  u32*   xrow = (u32*)p;   p += al256((size_t)Np * 64 * 4);        // bf16 rows of x
  u32*   aggx = (u32*)p;   p += al256((size_t)R * Np * 64 * 4);    // bf16 rows, per relation
  short* sbuf = (short*)p; p += al256((size_t)Np * DD * 2);
  short* dbuf = (short*)p; p += al256((size_t)Np * DD * 2);
  float* el   = (float*)p; p += al256((size_t)M * 4);
  float* er   = (float*)p; p += al256((size_t)M * 4);
  int*   cnt  = (int*)p;   p += al256((size_t)M * 4);
  int*   base = (int*)p;   p += al256(((size_t)M + 1) * 4);
  int*  eperm = (int*)p;   p += al256((size_t)R * E * 4);
  short* WA   = (short*)p; p += al256((size_t)R * 8 * 4 * 64 * 8 * 2);
  short* WB   = (short*)p; p += al256((size_t)2 * 8 * 4 * 64 * 8 * 2);
  float* wl   = (float*)p; p += al256((size_t)R * DD * 4);
  float* wr   = (float*)p; p += al256((size_t)R * DD * 4);
  int*   bsum = (int*)p;   p += 1024;
  int*   bpre = (int*)p;   p += 1024;

  const int egrid = (E + 255) / 256;

  k_prep_w<<<24, 256, 0, stream>>>(W, WA);
  k_prep_cw<<<16, 256, 0, stream>>>(bi_w, si_w, WB);
  k_prep_av<<<2, 192, 0, stream>>>(W, al, ar, wl, wr);
  k_prep_xrow<<<(N + 3) / 4, 256, 0, stream>>>(x, wl, wr, xrow, el, er, N);

  hipMemsetAsync(cnt, 0, (size_t)M * 4, stream);
  k_hist3<<<dim3(egrid, 3), 256, 0, stream>>>(edst, cnt, N, E);
  k_scan_bsum<<<NB, 256, 0, stream>>>(cnt, bsum, M);
  k_scan_btop<<<1, 256, 0, stream>>>(bsum, bpre, NB);
  k_scan_base<<<NB, 256, 0, stream>>>(cnt, bpre, base, M);
  k_scatter3<<<dim3(egrid, 3), 256, 0, stream>>>(edst, base, cnt, eperm, N, E);
  k_node_agg3<<<(N + 3) / 4, 256, 0, stream>>>(base, eperm, esrc, ew, el, er,
                                               xrow, aggx, N, Np, E);
  k_mfma_feats<<<Np / 64, 256, 0, stream>>>(aggx, WA, gb, sbuf, dbuf, N, Np);
  k_combine_mfma<<<Np / 128, 256, 0, stream>>>(
      sbuf, dbuf, x, WB, bi_b, si_b, res_w, ln_g, ln_b, (float*)d_out, N);
}

// Round 7
// 465.707 us; speedup vs baseline: 1.1205x; 1.1205x over previous
//
#include <hip/hip_runtime.h>

#define DD 128
typedef unsigned int u32;
typedef __attribute__((ext_vector_type(8))) short bf16x8;
typedef __attribute__((ext_vector_type(4))) float f32x4;

__device__ __forceinline__ float lrelu(float v, float s) { return v >= 0.f ? v : s * v; }
__device__ __forceinline__ ushort f2bf(float f) {
  union { float f; u32 u; } v; v.f = f;
  u32 u = v.u;
  return (ushort)((u + 0x7FFFu + ((u >> 16) & 1u)) >> 16);  // RNE
}

// ---------------- prep: W^T -> bf16 MFMA A-fragment layout ----------------
__global__ __launch_bounds__(256) void k_prep_w(const float* __restrict__ W,
                                                short* __restrict__ WA)
{
  int t = blockIdx.x * 256 + threadIdx.x;  // 6144
  int lane = t & 63, ks = (t >> 6) & 3, cf = (t >> 8) & 7, r = t >> 11;
  int c = cf * 16 + (lane & 15);
  int kb = ks * 32 + (lane >> 4) * 8;
  const float* Wr = W + (size_t)r * DD * DD;
  ushort o[8];
#pragma unroll
  for (int j = 0; j < 8; j++) o[j] = f2bf(Wr[(size_t)(kb + j) * DD + c]);
  uint4 st;
  st.x = (u32)o[0] | ((u32)o[1] << 16);
  st.y = (u32)o[2] | ((u32)o[3] << 16);
  st.z = (u32)o[4] | ((u32)o[5] << 16);
  st.w = (u32)o[6] | ((u32)o[7] << 16);
  *(uint4*)(WA + (size_t)t * 8) = st;
}

// ---------------- prep: bi_w/si_w -> bf16 A-frags ----------------
__global__ __launch_bounds__(256) void k_prep_cw(const float* __restrict__ bw,
                                                 const float* __restrict__ sw,
                                                 short* __restrict__ WB)
{
  int t = blockIdx.x * 256 + threadIdx.x;  // 4096
  int lane = t & 63, ks = (t >> 6) & 3, cf = (t >> 8) & 7, m = t >> 11;
  const float* src = m ? sw : bw;
  int c = cf * 16 + (lane & 15);
  int k = ks * 32 + (lane >> 4) * 8;
  const float* pr = src + (size_t)c * DD + k;
  uint4 st;
  st.x = (u32)f2bf(pr[0]) | ((u32)f2bf(pr[1]) << 16);
  st.y = (u32)f2bf(pr[2]) | ((u32)f2bf(pr[3]) << 16);
  st.z = (u32)f2bf(pr[4]) | ((u32)f2bf(pr[5]) << 16);
  st.w = (u32)f2bf(pr[6]) | ((u32)f2bf(pr[7]) << 16);
  *(uint4*)(WB + (size_t)t * 8) = st;
}

// ---------------- prep: wl = W @ attn_l, wr = W @ attn_r ----------------
__global__ void k_prep_av(const float* __restrict__ W, const float* __restrict__ al,
                          const float* __restrict__ ar, float* __restrict__ wl,
                          float* __restrict__ wr)
{
  int t = blockIdx.x * 192 + threadIdx.x;  // 384
  if (t >= 384) return;
  int r = t >> 7, k = t & 127;
  const float* Wrow = W + (size_t)r * DD * DD + (size_t)k * DD;
  const float* alr = al + r * DD;
  const float* arr = ar + r * DD;
  float pl = 0.f, pr = 0.f;
  for (int c = 0; c < DD; c++) { float w = Wrow[c]; pl = fmaf(w, alr[c], pl); pr = fmaf(w, arr[c], pr); }
  wl[t] = pl; wr[t] = pr;
}

// ---------------- prep: x -> bf16 rows + el/er = x.wl / x.wr ----------------
__global__ __launch_bounds__(256) void k_prep_xrow(
    const float* __restrict__ x, const float* __restrict__ wl, const float* __restrict__ wr,
    u32* __restrict__ xrow, float* __restrict__ el, float* __restrict__ er, int N)
{
  const int wid = (int)(((long long)blockIdx.x * 256 + threadIdx.x) >> 6);
  const int lane = threadIdx.x & 63;
  if (wid >= N) return;
  float2 xv = *(const float2*)(x + (size_t)wid * DD + lane * 2);
  xrow[(size_t)wid * 64 + lane] = (u32)f2bf(xv.x) | ((u32)f2bf(xv.y) << 16);
  float d[6];
#pragma unroll
  for (int r = 0; r < 3; r++) {
    float2 wlv = *(const float2*)(wl + r * DD + lane * 2);
    float2 wrv = *(const float2*)(wr + r * DD + lane * 2);
    d[r]     = xv.x * wlv.x + xv.y * wlv.y;
    d[r + 3] = xv.x * wrv.x + xv.y * wrv.y;
  }
#pragma unroll
  for (int o = 32; o; o >>= 1) {
#pragma unroll
    for (int k = 0; k < 6; k++) d[k] += __shfl_xor(d[k], o);
  }
  if (lane == 0) {
#pragma unroll
    for (int r = 0; r < 3; r++) {
      el[(size_t)r * N + wid] = d[r];
      er[(size_t)r * N + wid] = d[r + 3];
    }
  }
}

// ---------------- CSR build: histogram of dst (grid.y = r) ----------------
__global__ void k_hist3(const int* __restrict__ dst, int* __restrict__ cnt, int N, int E) {
  int i = blockIdx.x * 256 + threadIdx.x;
  int r = blockIdx.y;
  if (i < E) atomicAdd(cnt + (size_t)r * N + dst[(size_t)r * E + i], 1);
}

// ---------------- hierarchical scan: base[0..M] ----------------
__global__ __launch_bounds__(256) void k_scan_bsum(const int* __restrict__ cnt,
                                                   int* __restrict__ bsum, int M)
{
  __shared__ int red[256];
  const int t = threadIdx.x;
  const int g0 = blockIdx.x * 2048 + t * 8;
  int s = 0;
#pragma unroll
  for (int j = 0; j < 8; j++) { int i = g0 + j; if (i < M) s += cnt[i]; }
  red[t] = s;
  __syncthreads();
  for (int o = 128; o; o >>= 1) {
    if (t < o) red[t] += red[t + o];
    __syncthreads();
  }
  if (t == 0) bsum[blockIdx.x] = red[0];
}

__global__ __launch_bounds__(256) void k_scan_btop(const int* __restrict__ bsum,
                                                   int* __restrict__ bpre, int NB)
{
  __shared__ int sums[256];
  const int t = threadIdx.x;
  int v = (t < NB) ? bsum[t] : 0;
  sums[t] = v;
  __syncthreads();
  for (int o = 1; o < 256; o <<= 1) {
    int u = (t >= o) ? sums[t - o] : 0;
    __syncthreads();
    sums[t] += u;
    __syncthreads();
  }
  if (t < NB) bpre[t] = sums[t] - v;
}

__global__ __launch_bounds__(256) void k_scan_base(const int* __restrict__ cnt,
    const int* __restrict__ bpre, int* __restrict__ base, int M)
{
  __shared__ int sums[256];
  const int t = threadIdx.x;
  const int g0 = blockIdx.x * 2048 + t * 8;
  int c[8];
  int ts = 0;
#pragma unroll
  for (int j = 0; j < 8; j++) { int i = g0 + j; c[j] = (i < M) ? cnt[i] : 0; ts += c[j]; }
  sums[t] = ts;
  __syncthreads();
  for (int o = 1; o < 256; o <<= 1) {
    int u = (t >= o) ? sums[t - o] : 0;
    __syncthreads();
    sums[t] += u;
    __syncthreads();
  }
  int run = bpre[blockIdx.x] + sums[t] - ts;
#pragma unroll
  for (int j = 0; j < 8; j++) {
    int i = g0 + j;
    if (i <= M) base[i] = run;
    run += c[j];
  }
}

// ---------------- scatter: meta[pos] = (src, e=lrelu(el+er), ew) ----------------
__global__ void k_scatter3(const int* __restrict__ src, const int* __restrict__ dst,
    const float* __restrict__ ew, const float* __restrict__ el, const float* __restrict__ er,
    const int* __restrict__ base, int* __restrict__ cnt, int4* __restrict__ meta,
    int N, int E)
{
  int i = blockIdx.x * 256 + threadIdx.x;
  if (i >= E) return;
  int r = blockIdx.y;
  size_t ei = (size_t)r * E + i;
  int d = dst[ei], s = src[ei];
  size_t node = (size_t)r * N + d;
  int pos = base[node] + (atomicSub(cnt + node, 1) - 1);
  float e = lrelu(el[(size_t)r * N + s] + er[node], 0.2f);
  meta[pos] = make_int4(s, __float_as_int(e), __float_as_int(ew[ei]), 0);
}

// ---------------- per-node softmax(no-max)+x-aggregation, all 3 relations ----------------
// one wave per node; lane owns channels 2l,2l+1; chunk-0 of all relations peeled
// -> up to 24 row-gathers in flight.
__global__ __launch_bounds__(256) void k_node_agg3(
    const int* __restrict__ base, const int4* __restrict__ meta,
    const u32* __restrict__ xrow, u32* __restrict__ aggx, int N, int Np)
{
  const int wid = (int)(((long long)blockIdx.x * 256 + threadIdx.x) >> 6);
  const int lane = threadIdx.x & 63;
  if (wid >= N) return;
  const char* xb = (const char*)xrow;
  const u32 lb = (u32)lane << 2;

  int b0[3], dg[3];
#pragma unroll
  for (int r = 0; r < 3; r++) {
    int v0 = base[r * N + wid];
    int v1 = base[r * N + wid + 1];
    b0[r] = v0; dg[r] = v1 - v0;
  }

  float A0[3] = {0.f, 0.f, 0.f}, A1[3] = {0.f, 0.f, 0.f}, SS[3];

  if (dg[0] <= 64 && dg[1] <= 64 && dg[2] <= 64) {
    int sv[3]; float av[3], cwv[3];
#pragma unroll
    for (int r = 0; r < 3; r++) {
      int s = 0; float a = 0.f, c = 0.f;
      if (lane < dg[r]) {
        int4 mm = meta[b0[r] + lane];
        s = mm.x;
        a = __expf(fminf(__int_as_float(mm.y), 60.f));
        c = a * __int_as_float(mm.z);
      }
      sv[r] = s; av[r] = a; cwv[r] = c;
    }
    // ssum reduce (3 relations)
#pragma unroll
    for (int r = 0; r < 3; r++) {
      float s = av[r];
#pragma unroll
      for (int o = 32; o; o >>= 1) s += __shfl_xor(s, o);
      SS[r] = s;
    }
    // chunk 0 for all 3 relations: broadcasts then 24 independent loads
    float cc[3][8]; u32 oo[3][8];
#pragma unroll
    for (int r = 0; r < 3; r++)
#pragma unroll
      for (int q = 0; q < 8; q++) {
        cc[r][q] = __shfl(cwv[r], q);
        oo[r][q] = ((u32)__shfl(sv[r], q) << 8) | lb;
      }
    u32 uu[3][8];
#pragma unroll
    for (int r = 0; r < 3; r++)
#pragma unroll
      for (int q = 0; q < 8; q++) uu[r][q] = *(const u32*)(xb + oo[r][q]);
#pragma unroll
    for (int r = 0; r < 3; r++)
#pragma unroll
      for (int q = 0; q < 8; q++) {
        A0[r] = fmaf(cc[r][q], __uint_as_float(uu[r][q] << 16), A0[r]);
        A1[r] = fmaf(cc[r][q], __uint_as_float(uu[r][q] & 0xFFFF0000u), A1[r]);
      }
    // remaining chunks (deg > 8)
#pragma unroll
    for (int r = 0; r < 3; r++) {
      for (int c8 = 8; c8 < dg[r]; c8 += 8) {
        float c2[8]; u32 o2[8];
#pragma unroll
        for (int q = 0; q < 8; q++) {
          c2[q] = __shfl(cwv[r], c8 + q);
          o2[q] = ((u32)__shfl(sv[r], c8 + q) << 8) | lb;
        }
        u32 u2[8];
#pragma unroll
        for (int q = 0; q < 8; q++) u2[q] = *(const u32*)(xb + o2[q]);
#pragma unroll
        for (int q = 0; q < 8; q++) {
          A0[r] = fmaf(c2[q], __uint_as_float(u2[q] << 16), A0[r]);
          A1[r] = fmaf(c2[q], __uint_as_float(u2[q] & 0xFFFF0000u), A1[r]);
        }
      }
    }
  } else {
    // generic fallback (deg > 64 somewhere)
#pragma unroll
    for (int r = 0; r < 3; r++) {
      float sp = 0.f;
      for (int c0 = 0; c0 < dg[r]; c0 += 64) {
        int kk = min(64, dg[r] - c0);
        int s = 0; float a = 0.f, c = 0.f;
        if (lane < kk) {
          int4 mm = meta[b0[r] + c0 + lane];
          s = mm.x;
          a = __expf(fminf(__int_as_float(mm.y), 60.f));
          c = a * __int_as_float(mm.z);
        }
        sp += a;
        for (int c8 = 0; c8 < kk; c8 += 8) {
          float c2[8]; u32 o2[8];
#pragma unroll
          for (int q = 0; q < 8; q++) {
            c2[q] = __shfl(c, c8 + q);
            o2[q] = ((u32)__shfl(s, c8 + q) << 8) | lb;
          }
          u32 u2[8];
#pragma unroll
          for (int q = 0; q < 8; q++) u2[q] = *(const u32*)(xb + o2[q]);
#pragma unroll
          for (int q = 0; q < 8; q++) {
            A0[r] = fmaf(c2[q], __uint_as_float(u2[q] << 16), A0[r]);
            A1[r] = fmaf(c2[q], __uint_as_float(u2[q] & 0xFFFF0000u), A1[r]);
          }
        }
      }
#pragma unroll
      for (int o = 32; o; o >>= 1) sp += __shfl_xor(sp, o);
      SS[r] = sp;
    }
  }

#pragma unroll
  for (int r = 0; r < 3; r++) {
    const float inv = (dg[r] > 0) ? 1.f / SS[r] : 0.f;
    aggx[((size_t)r * Np + wid) * 64 + lane] =
        (u32)f2bf(A0[r] * inv) | ((u32)f2bf(A1[r] * inv) << 16);
  }
}

// ---------------- fused tail: feats MFMA -> LDS relayout -> combine MFMA + LN ----------------
// 4 waves x 16 nodes per block.
__global__ __launch_bounds__(256) void k_tail(
    const u32* __restrict__ aggx, const short* __restrict__ WA,
    const float* __restrict__ gb, const float* __restrict__ x,
    const short* __restrict__ WB, const float* __restrict__ bi_b,
    const float* __restrict__ si_b, const float* __restrict__ res_w,
    const float* __restrict__ ln_g, const float* __restrict__ ln_b,
    float* __restrict__ out, int N, int Np)
{
  __shared__ u32 lds_s[4][16][68];   // [wave][node][word], +4 pad words per row
  __shared__ u32 lds_d[4][16][68];
  const int lane = threadIdx.x & 63;
  const int w = threadIdx.x >> 6;
  const int nl = lane & 15;
  const int fh = lane >> 4;          // 0..3
  const int n0 = blockIdx.x * 64 + w * 16;
  const int node = n0 + nl;
  const short* ax = (const short*)aggx;

  // ---- feats: s = sum_r (aggx_r @ W_r + gb_r), q = sum of squares ----
  f32x4 sa[8], qa[8];
#pragma unroll
  for (int cf = 0; cf < 8; cf++) { sa[cf] = (f32x4){0,0,0,0}; qa[cf] = (f32x4){0,0,0,0}; }

  for (int r = 0; r < 3; r++) {
    bf16x8 bf[4];
#pragma unroll
    for (int ks = 0; ks < 4; ks++)
      bf[ks] = *(const bf16x8*)(ax + ((size_t)r * Np + node) * DD + ks * 32 + fh * 8);
    f32x4 acc[8];
#pragma unroll
    for (int cf = 0; cf < 8; cf++) acc[cf] = (f32x4){0,0,0,0};
#pragma unroll
    for (int ks = 0; ks < 4; ks++) {
#pragma unroll
      for (int cf = 0; cf < 8; cf++) {
        bf16x8 af = *(const bf16x8*)(WA + ((((size_t)r * 8 + cf) * 4 + ks) * 64 + lane) * 8);
        acc[cf] = __builtin_amdgcn_mfma_f32_16x16x32_bf16(af, bf[ks], acc[cf], 0, 0, 0);
      }
    }
#pragma unroll
    for (int cf = 0; cf < 8; cf++) {
      float4 g4 = *(const float4*)(gb + r * DD + cf * 16 + fh * 4);
      const float* gp = (const float*)&g4;
#pragma unroll
      for (int j = 0; j < 4; j++) {
        float f = acc[cf][j] + gp[j];
        sa[cf][j] += f;
        qa[cf][j] += f * f;
      }
    }
  }

  // ---- write s, dfm rows to LDS (C-layout -> row-major bf16) ----
#pragma unroll
  for (int cf = 0; cf < 8; cf++) {
    int wb = cf * 8 + fh * 2;
    float d0 = 0.5f * (sa[cf][0] * sa[cf][0] - qa[cf][0]);
    float d1 = 0.5f * (sa[cf][1] * sa[cf][1] - qa[cf][1]);
    float d2 = 0.5f * (sa[cf][2] * sa[cf][2] - qa[cf][2]);
    float d3 = 0.5f * (sa[cf][3] * sa[cf][3] - qa[cf][3]);
    lds_s[w][nl][wb]     = (u32)f2bf(sa[cf][0]) | ((u32)f2bf(sa[cf][1]) << 16);
    lds_s[w][nl][wb + 1] = (u32)f2bf(sa[cf][2]) | ((u32)f2bf(sa[cf][3]) << 16);
    lds_d[w][nl][wb]     = (u32)f2bf(d0) | ((u32)f2bf(d1) << 16);
    lds_d[w][nl][wb + 1] = (u32)f2bf(d2) | ((u32)f2bf(d3) << 16);
  }
  __syncthreads();

  // ---- combine: read B-frags from LDS ----
  union { uint4 u; bf16x8 h; } cvt;
  bf16x8 sf[4], df[4];
#pragma unroll
  for (int ks = 0; ks < 4; ks++) {
    cvt.u = *(const uint4*)&lds_s[w][nl][ks * 16 + fh * 4];
    sf[ks] = cvt.h;
    cvt.u = *(const uint4*)&lds_d[w][nl][ks * 16 + fh * 4];
    df[ks] = cvt.h;
  }
  f32x4 accB[8], accS[8];
#pragma unroll
  for (int cf = 0; cf < 8; cf++) {
    accB[cf] = (f32x4){0,0,0,0};
    accS[cf] = (f32x4){0,0,0,0};
  }
#pragma unroll
  for (int ks = 0; ks < 4; ks++) {
#pragma unroll
    for (int cf = 0; cf < 8; cf++) {
      bf16x8 ab = *(const bf16x8*)(WB + ((((size_t)0 * 8 + cf) * 4 + ks) * 64 + lane) * 8);
      bf16x8 as = *(const bf16x8*)(WB + ((((size_t)1 * 8 + cf) * 4 + ks) * 64 + lane) * 8);
      accB[cf] = __builtin_amdgcn_mfma_f32_16x16x32_bf16(ab, df[ks], accB[cf], 0, 0, 0);
      accS[cf] = __builtin_amdgcn_mfma_f32_16x16x32_bf16(as, sf[ks], accS[cf], 0, 0, 0);
    }
  }

  const float sigw = 1.f / (1.f + __expf(-res_w[0]));
  float vals[8][4];
  float sv = 0.f, sq = 0.f;
#pragma unroll
  for (int cf = 0; cf < 8; cf++) {
    int c0 = cf * 16 + fh * 4;
    float4 bb4 = *(const float4*)(bi_b + c0);
    float4 sb4 = *(const float4*)(si_b + c0);
    float4 xv = make_float4(0.f, 0.f, 0.f, 0.f);
    if (node < N) xv = *(const float4*)(x + (size_t)node * DD + c0);
    const float* bbp = (const float*)&bb4;
    const float* sbp = (const float*)&sb4;
    const float* xvp = (const float*)&xv;
#pragma unroll
    for (int j = 0; j < 4; j++) {
      float val = lrelu(accB[cf][j] + bbp[j], 0.01f)
                + lrelu(accS[cf][j] + sbp[j], 0.01f)
                + xvp[j] * sigw;
      vals[cf][j] = val;
      sv += val; sq += val * val;
    }
  }
  sv += __shfl_xor(sv, 16); sq += __shfl_xor(sq, 16);
  sv += __shfl_xor(sv, 32); sq += __shfl_xor(sq, 32);
  const float mu = sv * (1.f / DD);
  const float var = sq * (1.f / DD) - mu * mu;
  const float rs = rsqrtf(var + 1e-5f);
  if (node < N) {
#pragma unroll
    for (int cf = 0; cf < 8; cf++) {
      int c0 = cf * 16 + fh * 4;
      float4 g4 = *(const float4*)(ln_g + c0);
      float4 b4 = *(const float4*)(ln_b + c0);
      float4 o;
      o.x = (vals[cf][0] - mu) * rs * g4.x + b4.x;
      o.y = (vals[cf][1] - mu) * rs * g4.y + b4.y;
      o.z = (vals[cf][2] - mu) * rs * g4.z + b4.z;
      o.w = (vals[cf][3] - mu) * rs * g4.w + b4.w;
      *(float4*)(out + (size_t)node * DD + c0) = o;
    }
  }
}

extern "C" void kernel_launch(void* const* d_in, const int* in_sizes, int n_in,
                              void* d_out, int out_size, void* d_ws, size_t ws_size,
                              hipStream_t stream)
{
  const float* x    = (const float*)d_in[0];
  const int*   esrc = (const int*)d_in[1];
  const int*   edst = (const int*)d_in[2];
  const float* ew   = (const float*)d_in[3];
  const float* W    = (const float*)d_in[4];
  const float* al   = (const float*)d_in[5];
  const float* ar   = (const float*)d_in[6];
  const float* gb   = (const float*)d_in[7];
  const float* bi_w = (const float*)d_in[8];
  const float* bi_b = (const float*)d_in[9];
  const float* si_w = (const float*)d_in[10];
  const float* si_b = (const float*)d_in[11];
  const float* res_w= (const float*)d_in[12];
  const float* ln_g = (const float*)d_in[13];
  const float* ln_b = (const float*)d_in[14];

  const int N = in_sizes[0] / DD;
  const int R = 3;
  const int E = in_sizes[1] / R;
  const int Np = ((N + 127) / 128) * 128;
  const int M = R * N;
  const int NB = (M + 2047) / 2048;

  auto al256 = [](size_t v) { return (v + 255) & ~(size_t)255; };
  char* p = (char*)d_ws;
  u32*   xrow = (u32*)p;   p += al256((size_t)Np * 64 * 4);
  u32*   aggx = (u32*)p;   p += al256((size_t)R * Np * 64 * 4);
  int4*  meta = (int4*)p;  p += al256((size_t)R * E * 16);
  float* el   = (float*)p; p += al256((size_t)M * 4);
  float* er   = (float*)p; p += al256((size_t)M * 4);
  int*   cnt  = (int*)p;   p += al256((size_t)M * 4);
  int*   base = (int*)p;   p += al256(((size_t)M + 1) * 4);
  short* WA   = (short*)p; p += al256((size_t)R * 8 * 4 * 64 * 8 * 2);
  short* WB   = (short*)p; p += al256((size_t)2 * 8 * 4 * 64 * 8 * 2);
  float* wl   = (float*)p; p += al256((size_t)R * DD * 4);
  float* wr   = (float*)p; p += al256((size_t)R * DD * 4);
  int*   bsum = (int*)p;   p += 1024;
  int*   bpre = (int*)p;   p += 1024;

  const int egrid = (E + 255) / 256;

  k_prep_w<<<24, 256, 0, stream>>>(W, WA);
  k_prep_cw<<<16, 256, 0, stream>>>(bi_w, si_w, WB);
  k_prep_av<<<2, 192, 0, stream>>>(W, al, ar, wl, wr);
  k_prep_xrow<<<(N + 3) / 4, 256, 0, stream>>>(x, wl, wr, xrow, el, er, N);

  hipMemsetAsync(cnt, 0, (size_t)M * 4, stream);
  k_hist3<<<dim3(egrid, 3), 256, 0, stream>>>(edst, cnt, N, E);
  k_scan_bsum<<<NB, 256, 0, stream>>>(cnt, bsum, M);
  k_scan_btop<<<1, 256, 0, stream>>>(bsum, bpre, NB);
  k_scan_base<<<NB, 256, 0, stream>>>(cnt, bpre, base, M);
  k_scatter3<<<dim3(egrid, 3), 256, 0, stream>>>(esrc, edst, ew, el, er,
                                                 base, cnt, meta, N, E);
  k_node_agg3<<<(N + 3) / 4, 256, 0, stream>>>(base, meta, xrow, aggx, N, Np);
  k_tail<<<Np / 64, 256, 0, stream>>>(aggx, WA, gb, x, WB, bi_b, si_b,
                                      res_w, ln_g, ln_b, (float*)d_out, N, Np);
}